// Round 4
// baseline (130.530 us; speedup 1.0000x reference)
//
#include <hip/hip_runtime.h>
#include <math.h>

// VectorQuantizer — bit-exact emulation of the numpy fp32 reference (proven R2-R11):
//   d[n,k] = fl32( fl32(x2[n]+c2[k]) - fl32(2 * fl32(exact_fp64_dot)) ), first argmin.
//
// R16: single-pass filter. R15 recomputed ~87% of tiles in phase 2 (every row's
// own min passes the THR filter -> tile-skip ballot never fires) and spent more
// VALU than MFMA on min tracking. R16:
//   * accumulator seeded with -c2/2  =>  w = dot - c2/2; argmin(d) = argmax(w)
//     (exact monotone -2x map). One FMA/elem, no c2 epilogue.
//   * (tile,nsub) packed into the 7 low mantissa bits of w (perturb <=1.5e-7
//     << THRW): the running max IS the argmax code. No cndmask, no phase 2,
//     no candidate-list atomics.
//   * per-row streaming top-2 (m1,m2); row unambiguous iff m1-m2 > THRW=6e-5
//     (filter err ~1e-6 + reference fp32-quantization ~8e-6 in w-space: 6x
//     margin) -> packed winner == exact argmin, provably.
//   * ambiguous rows (~1-3/block): ALL 512 codes resolved with the verbatim
//     R12 fp64 resolver, 256 threads x 2 codes. Flag list via wave-0 ballot.

#define N_CODES   512
#define CODE_DIM  64
#define CH_STRIDE 4096                      // floats between channels
#define B_STRIDE  (CODE_DIM * CH_STRIDE)    // floats between batches
#define XPITCH    68                        // xs row pitch (mult of 4)
#define THRW      6.0e-5f                   // w-space threshold (= THR/2 of R12-R15)

typedef _Float16 f16x8 __attribute__((ext_vector_type(8)));
typedef float    f32x4 __attribute__((ext_vector_type(4)));

__device__ __forceinline__ unsigned short f16_bits(_Float16 h) {
    union { _Float16 f; unsigned short u; } cv; cv.f = h; return cv.u;
}

__device__ __forceinline__ uint4 pack8u16(const unsigned short* s) {
    uint4 v;
    v.x = (unsigned)s[0] | ((unsigned)s[1] << 16);
    v.y = (unsigned)s[2] | ((unsigned)s[3] << 16);
    v.z = (unsigned)s[4] | ((unsigned)s[5] << 16);
    v.w = (unsigned)s[6] | ((unsigned)s[7] << 16);
    return v;
}

// ---------------- setup: c2 (numpy pairwise) + f16 hi/lo B-frag tables ------
__device__ __forceinline__ float np_pairwise_sum64(const float* a) {
    float r[8];
#pragma unroll
    for (int j = 0; j < 8; ++j) r[j] = a[j];
#pragma unroll
    for (int i = 8; i < 64; i += 8) {
#pragma unroll
        for (int j = 0; j < 8; ++j) r[j] = __fadd_rn(r[j], a[i + j]);
    }
    return __fadd_rn(__fadd_rn(__fadd_rn(r[0], r[1]), __fadd_rn(r[2], r[3])),
                     __fadd_rn(__fadd_rn(r[4], r[5]), __fadd_rn(r[6], r[7])));
}

// B-frag tables in exact MFMA B-operand order (16x16x32: n=lane&15,
// k=(lane>>4)*8+j): element index ((T*2+kk)*64 + lane)*8 + j  maps to
// cb[T*16 + (lane&15)][kk*32 + (lane>>4)*8 + j].  (verified: R13-R15 absmax=0)
__global__ void vq_setup_kernel(const float* __restrict__ cb, float* __restrict__ c2,
                                unsigned short* __restrict__ bh,
                                unsigned short* __restrict__ bl, int buildT) {
    const int t = blockIdx.x * blockDim.x + threadIdx.x;   // 64 blocks x 64 = 4096
    if (buildT) {
        const int l    = t & 63;
        const int kkT  = t >> 6;                           // T*2+kk, 0..63
        const int code = (kkT >> 1) * 16 + (l & 15);
        const int d0   = (kkT & 1) * 32 + ((l >> 4) << 3);
        const float* crow = cb + code * CODE_DIM + d0;
        unsigned short hs[8], ls[8];
#pragma unroll
        for (int j = 0; j < 8; ++j) {
            const float c  = crow[j];
            const _Float16 h = (_Float16)c;                 // RNE
            const float lf = __fsub_rn(c, (float)h) * 4096.0f;  // exact (Sterbenz + pow2)
            hs[j] = f16_bits(h);
            ls[j] = f16_bits((_Float16)lf);                 // scaled lo: stays f16-normal
        }
        const uint4 hv = pack8u16(hs), lv = pack8u16(ls);
        *(uint4*)(bh + (size_t)t * 8) = hv;
        *(uint4*)(bl + (size_t)t * 8) = lv;
    }
    if (t < N_CODES) {
        const float* row = cb + t * CODE_DIM;
        float sq[CODE_DIM];
#pragma unroll
        for (int j = 0; j < CODE_DIM; ++j) sq[j] = __fmul_rn(row[j], row[j]);
        c2[t] = np_pairwise_sum64(sq);
    }
}

// Rare-path exact resolver — VERBATIM R12 arithmetic (bit-exact proven):
// reads only LDS (xs, s_x2e, s_res) and global (cb, c2). __noinline__, one
// hot call site; caller has no live register arrays across the call.
__device__ __noinline__ void resolve_cell(const float* __restrict__ cb,
                                          const float* __restrict__ c2g,
                                          const float* xs_base,      // &xs[0][0]
                                          const float* s_x2e,
                                          unsigned long long* s_res,
                                          int row, int k) {
    const float* crow = cb + (size_t)k * CODE_DIM;
    double b0 = 0.0, b1 = 0.0, b2 = 0.0, b3 = 0.0;
#pragma unroll
    for (int c = 0; c < CODE_DIM; c += 4) {
        b0 = fma((double)crow[c + 0], (double)xs_base[(c + 0) * XPITCH + row], b0);
        b1 = fma((double)crow[c + 1], (double)xs_base[(c + 1) * XPITCH + row], b1);
        b2 = fma((double)crow[c + 2], (double)xs_base[(c + 2) * XPITCH + row], b2);
        b3 = fma((double)crow[c + 3], (double)xs_base[(c + 3) * XPITCH + row], b3);
    }
    const double dot64 = (b0 + b1) + (b2 + b3);
    const float  ein   = (float)dot64;
    const float  tmp   = __fadd_rn(s_x2e[row], c2g[k]);
    const float  dk    = __fsub_rn(tmp, __fmul_rn(2.0f, ein));
    const unsigned u     = __float_as_uint(dk);
    const unsigned key32 = (u & 0x80000000u) ? ~u : (u | 0x80000000u);
    atomicMin(&s_res[row], ((unsigned long long)key32 << 32) | (unsigned)k);
}

// ---------------- main: single-pass MFMA argmax filter + exact resolve ------
// Block = one (b,h) group: 64 rows x 512 codes, 256 threads (4 waves).
// Wave wid: ALL 64 rows (4 M-tiles) x codes [wid*128, wid*128+128) (8 N-tiles).
__global__ __launch_bounds__(256, 2)
void vq_block_kernel(const float* __restrict__ in,
                     const float* __restrict__ cb,
                     const float* __restrict__ c2g,
                     const unsigned short* __restrict__ bhT,
                     const unsigned short* __restrict__ blT,
                     float* __restrict__ out) {
    __shared__ __align__(16) float xs[CODE_DIM][XPITCH];   // x-tile [dim][row], 17.4KB
    __shared__ float s_wm1[4][64];                         // per-wave row max (packed)
    __shared__ float s_wm2[4][64];                         // per-wave row 2nd-max
    __shared__ float s_x2e[64];                            // numpy-exact x2 per row
    __shared__ int   s_win[64];                            // winner code or -1
    __shared__ int   s_flag[64];                           // flagged-row list
    __shared__ int   s_nflag;
    __shared__ unsigned long long s_res[64];               // packed (dk-key, k)

    const int tid  = threadIdx.x;
    const int lane = tid & 63;
    const int wid  = tid >> 6;               // 0..3
    const int gw   = blockIdx.x;             // (b,h) group 0..1023
    const float* src = in + (size_t)(gw >> 6) * B_STRIDE + (size_t)(gw & 63) * 64;

    // --- stage x-tile: xs[c][r] = src[c*4096 + r]; float4 slots, coalesced --
#pragma unroll
    for (int i = 0; i < 4; ++i) {
        const int s = tid + (i << 8);
        const int c = s >> 4, q = s & 15;
        *(float4*)&xs[c][q * 4] = *(const float4*)(src + (size_t)c * CH_STRIDE + q * 4);
    }
    if (tid < 64) s_res[tid] = ~0ull;
    __syncthreads();

    // --- numpy-exact x2 per row (R5-proven rolling 8-acc pairwise order) ----
    if (tid < 64) {
        float r[8];
#pragma unroll
        for (int j = 0; j < 8; ++j) r[j] = __fmul_rn(xs[j][tid], xs[j][tid]);
#pragma unroll
        for (int i = 8; i < 64; i += 8) {
#pragma unroll
            for (int j = 0; j < 8; ++j)
                r[j] = __fadd_rn(r[j], __fmul_rn(xs[i + j][tid], xs[i + j][tid]));
        }
        s_x2e[tid] = __fadd_rn(
            __fadd_rn(__fadd_rn(r[0], r[1]), __fadd_rn(r[2], r[3])),
            __fadd_rn(__fadd_rn(r[4], r[5]), __fadd_rn(r[6], r[7])));
    }

    // --- A-frags from LDS (m=lane&15, k=(lane>>4)*8+j; R13-R15-verified) ----
    f16x8 Ah[4][2], Al[4][2];
#pragma unroll
    for (int mt = 0; mt < 4; ++mt)
#pragma unroll
        for (int kk = 0; kk < 2; ++kk)
#pragma unroll
            for (int j = 0; j < 8; ++j) {
                const int d = (kk << 5) + ((lane >> 4) << 3) + j;
                const float x = xs[d][(mt << 4) + (lane & 15)];
                const _Float16 h = (_Float16)x;
                const float lf = __fsub_rn(x, (float)h) * 4096.0f;
                Ah[mt][kk][j] = h;
                Al[mt][kk][j] = (_Float16)lf;
            }

    const int nsub  = lane & 15;
    const int rbase = (lane >> 4) << 2;      // row-in-tile base for D-layout

    // accumulator seeds: -c2/2 per tile (exact pow2 scale)
    float seed[8];
#pragma unroll
    for (int t = 0; t < 8; ++t)
        seed[t] = -0.5f * c2g[(((wid << 3) + t) << 4) + nsub];

    // --- single-pass scan: w = dot - c2/2; track packed (m1, m2) per row ----
    float m1[16], m2[16];
#pragma unroll
    for (int i = 0; i < 16; ++i) { m1[i] = -1e30f; m2[i] = -1e30f; }

#pragma unroll
    for (int t = 0; t < 8; ++t) {
        const int T2 = (((wid << 3) + t) << 1);
        const f16x8 Bh0 = *(const f16x8*)(bhT + ((size_t)(T2 + 0) * 64 + lane) * 8);
        const f16x8 Bh1 = *(const f16x8*)(bhT + ((size_t)(T2 + 1) * 64 + lane) * 8);
        const f16x8 Bl0 = *(const f16x8*)(blT + ((size_t)(T2 + 0) * 64 + lane) * 8);
        const f16x8 Bl1 = *(const f16x8*)(blT + ((size_t)(T2 + 1) * 64 + lane) * 8);
        const float sd = seed[t];
        const unsigned pk = ((unsigned)t << 4) | (unsigned)nsub;   // 7 low bits
#pragma unroll
        for (int mt = 0; mt < 4; ++mt) {
            f32x4 a1 = {sd, sd, sd, sd};
            f32x4 a2 = {0.f, 0.f, 0.f, 0.f};
            a1 = __builtin_amdgcn_mfma_f32_16x16x32_f16(Ah[mt][0], Bh0, a1, 0, 0, 0);
            a1 = __builtin_amdgcn_mfma_f32_16x16x32_f16(Ah[mt][1], Bh1, a1, 0, 0, 0);
            a2 = __builtin_amdgcn_mfma_f32_16x16x32_f16(Al[mt][0], Bh0, a2, 0, 0, 0);
            a2 = __builtin_amdgcn_mfma_f32_16x16x32_f16(Ah[mt][0], Bl0, a2, 0, 0, 0);
            a2 = __builtin_amdgcn_mfma_f32_16x16x32_f16(Al[mt][1], Bh1, a2, 0, 0, 0);
            a2 = __builtin_amdgcn_mfma_f32_16x16x32_f16(Ah[mt][1], Bl1, a2, 0, 0, 0);
#pragma unroll
            for (int r = 0; r < 4; ++r) {
                const float w  = __fmaf_rn(2.44140625e-4f, a2[r], a1[r]);  // +2^-12*lo
                const float wq = __uint_as_float(
                    (__float_as_uint(w) & 0xFFFFFF80u) | pk);
                const int i = (mt << 2) + r;
                m2[i] = fmaxf(m2[i], fminf(m1[i], wq));    // streaming top-2
                m1[i] = fmaxf(m1[i], wq);
            }
        }
    }

    // --- top-2 reduce over the 16 code-lanes of each group ------------------
#pragma unroll
    for (int s = 1; s < 16; s <<= 1)
#pragma unroll
        for (int i = 0; i < 16; ++i) {
            const float o1 = __shfl_xor(m1[i], s, 64);
            const float o2 = __shfl_xor(m2[i], s, 64);
            m2[i] = fmaxf(fmaxf(m2[i], o2), fminf(m1[i], o1));
            m1[i] = fmaxf(m1[i], o1);
        }
    if (nsub == 0) {
#pragma unroll
        for (int mt = 0; mt < 4; ++mt)
#pragma unroll
            for (int r = 0; r < 4; ++r) {
                const int row = (mt << 4) + rbase + r;
                s_wm1[wid][row] = m1[(mt << 2) + r];
                s_wm2[wid][row] = m2[(mt << 2) + r];
            }
    }
    __syncthreads();

    // --- combine 4 waves (wave 0 only), decide winner or flag ---------------
    if (tid < 64) {
        float g1 = s_wm1[0][tid], g2 = s_wm2[0][tid];
        int wsel = 0;
#pragma unroll
        for (int w = 1; w < 4; ++w) {
            const float a = s_wm1[w][tid];
            const float b = s_wm2[w][tid];
            g2 = fmaxf(fmaxf(g2, b), fminf(g1, a));
            wsel = (a > g1) ? w : wsel;
            g1 = fmaxf(g1, a);
        }
        const bool flag = (g1 - g2) <= THRW;   // ambiguous -> exact resolve
        if (!flag) {
            const unsigned u = __float_as_uint(g1);
            s_win[tid] = (wsel << 7) | (((u >> 4) & 7u) << 4) | (u & 15u);
        } else {
            s_win[tid] = -1;
        }
        const unsigned long long mask = __ballot(flag);   // wave 0 = tids 0..63
        const int pos = __popcll(mask & ((1ull << lane) - 1ull));
        if (flag) s_flag[pos] = tid;
        if (tid == 0) s_nflag = __popcll(mask);
    }
    __syncthreads();

    // --- exact fp64 resolve for flagged rows: all 512 codes, 256 threads ----
    const int nf = s_nflag;
    for (int e = 0; e < nf; ++e) {
        const int row = s_flag[e];
        resolve_cell(cb, c2g, &xs[0][0], s_x2e, s_res, row, tid);
        resolve_cell(cb, c2g, &xs[0][0], s_x2e, s_res, row, tid + 256);
    }
    __syncthreads();

    // --- output: wave wid writes rows wid*16..+15 (coalesced 256B each) -----
    const size_t n0 = (size_t)gw * 64;
#pragma unroll
    for (int rr = 0; rr < 16; ++rr) {
        const int row = (wid << 4) + rr;
        const int win = s_win[row];
        const int idx = (win >= 0) ? win : (int)(s_res[row] & 0xFFFFFFFFull);
        out[(n0 + row) * CODE_DIM + lane] = cb[(size_t)idx * CODE_DIM + lane];
    }
}

// ---------------- fallback (R9, proven 190us) if ws too small ---------------
__device__ __forceinline__ float exact_dk_fb(const float* __restrict__ cb,
                                             const float* __restrict__ c2,
                                             const float (&x)[CODE_DIM], float x2, int k) {
    const float* crow = cb + (size_t)k * CODE_DIM;
    double a0 = 0.0, a1 = 0.0, a2 = 0.0, a3 = 0.0;
#pragma unroll
    for (int j = 0; j < CODE_DIM; j += 4) {
        a0 = fma((double)crow[j + 0], (double)x[j + 0], a0);
        a1 = fma((double)crow[j + 1], (double)x[j + 1], a1);
        a2 = fma((double)crow[j + 2], (double)x[j + 2], a2);
        a3 = fma((double)crow[j + 3], (double)x[j + 3], a3);
    }
    const double dot = (a0 + a1) + (a2 + a3);
    const float  ein = (float)dot;
    return __fsub_rn(__fadd_rn(x2, c2[k]), __fmul_rn(2.0f, ein));
}

__global__ __launch_bounds__(512, 2)
void vq_fallback_kernel(const float* __restrict__ in, const float* __restrict__ cb,
                        const float* __restrict__ c2, float* __restrict__ out) {
    __shared__ float s_rb[8][64];
    __shared__ int   s_ri[8][64];
    const int tid = threadIdx.x, lane = tid & 63, wid = tid >> 6;
    const int gw = blockIdx.x, b = gw >> 6, h = gw & 63;
    const float* xin = in + (size_t)b * B_STRIDE + (size_t)h * 64 + lane;
    float x[CODE_DIM];
#pragma unroll
    for (int c = 0; c < CODE_DIM; ++c) x[c] = xin[(size_t)c * CH_STRIDE];
    float r[8];
#pragma unroll
    for (int j = 0; j < 8; ++j) r[j] = __fmul_rn(x[j], x[j]);
#pragma unroll
    for (int i = 8; i < 64; i += 8)
#pragma unroll
        for (int j = 0; j < 8; ++j) r[j] = __fadd_rn(r[j], __fmul_rn(x[i + j], x[i + j]));
    const float x2 = __fadd_rn(__fadd_rn(__fadd_rn(r[0], r[1]), __fadd_rn(r[2], r[3])),
                               __fadd_rn(__fadd_rn(r[4], r[5]), __fadd_rn(r[6], r[7])));
    const int k0 = __builtin_amdgcn_readfirstlane(wid) * 64;
    float ex_best = INFINITY; int bi = k0;
#pragma unroll 1
    for (int kk = 0; kk < 64; ++kk) {
        const float dk = exact_dk_fb(cb, c2, x, x2, k0 + kk);
        if (dk < ex_best) { ex_best = dk; bi = k0 + kk; }
    }
    s_rb[wid][lane] = ex_best; s_ri[wid][lane] = bi;
    __syncthreads();
    float fb2 = s_rb[0][lane]; int fi = s_ri[0][lane];
#pragma unroll
    for (int w = 1; w < 8; ++w) {
        if (s_rb[w][lane] < fb2) { fb2 = s_rb[w][lane]; fi = s_ri[w][lane]; }
    }
    const size_t n0 = (size_t)gw * 64;
#pragma unroll 1
    for (int rr = 0; rr < 8; ++rr) {
        const int row = wid * 8 + rr;
        const int idxr = __shfl(fi, row, 64);
        out[(n0 + row) * CODE_DIM + lane] = cb[(size_t)idxr * CODE_DIM + lane];
    }
}

extern "C" void kernel_launch(void* const* d_in, const int* in_sizes, int n_in,
                              void* d_out, int out_size, void* d_ws, size_t ws_size,
                              hipStream_t stream) {
    const float* in  = (const float*)d_in[0];   // (16,64,64,64) fp32
    const float* cb  = (const float*)d_in[1];   // (512,64) fp32
    float*       out = (float*)d_out;           // (16,64,64,64) fp32

    float* c2 = (float*)d_ws;                                    // 2 KB
    unsigned short* bh = (unsigned short*)((char*)d_ws + 2048);  // 64 KB f16-hi frags
    unsigned short* bl = (unsigned short*)((char*)d_ws + 2048 + 65536);  // 64 KB f16-lo
    const bool hasT = ws_size >= (size_t)(2048 + 2 * 65536);     // 133120 B

    vq_setup_kernel<<<dim3(64), dim3(64), 0, stream>>>(cb, c2, bh, bl, hasT ? 1 : 0);
    if (hasT) {
        // 1024 blocks = one (b,h) group (64 rows) each; 256 threads = 4 waves.
        vq_block_kernel<<<dim3(1024), dim3(256), 0, stream>>>(in, cb, c2, bh, bl, out);
    } else {
        vq_fallback_kernel<<<dim3(1024), dim3(512), 0, stream>>>(in, cb, c2, out);
    }
}

// Round 5
// 113.369 us; speedup vs baseline: 1.1514x; 1.1514x over previous
//
#include <hip/hip_runtime.h>
#include <math.h>

// VectorQuantizer — bit-exact emulation of the numpy fp32 reference (proven R2-R11):
//   d[n,k] = fl32( fl32(x2[n]+c2[k]) - fl32(2 * fl32(exact_fp64_dot)) ), first argmin.
//
// R17: revert to R15's proven two-phase skeleton (59us; R16's single-pass
// regressed to 72us with doubled bank conflicts + doubled shfl reduce +
// 512-code resolver stragglers). Two surgical changes, both attributable:
//   * shared A-frag build: x -> f16 hi/lo converted ONCE per block into LDS
//     aHi/aLo[4][2][512] (R13-verified layout), 256 thr x 2 planes each.
//     Replaces per-wave 64 conflicted scalar LDS reads + ~320 VALU (x4 waves
//     redundant) with 16 conflict-free ds_read_b128 per thread.
//   * c2 staged in LDS: phase-1/2 c2v reads become LDS broadcasts.
// Phase-1/phase-2/resolver/output numerics verbatim R15 (absmax=0 proven).

#define N_CODES   512
#define CODE_DIM  64
#define CH_STRIDE 4096                      // floats between channels
#define B_STRIDE  (CODE_DIM * CH_STRIDE)    // floats between batches
#define XPITCH    68                        // xs row pitch (mult of 4)
#define THR       1.2e-4f                   // >= 2*(dk-formula rounding + filter err)
#define CAP       160                       // candidate-list capacity

typedef _Float16 f16x8 __attribute__((ext_vector_type(8)));
typedef float    f32x4 __attribute__((ext_vector_type(4)));

__device__ __forceinline__ unsigned short f16_bits(_Float16 h) {
    union { _Float16 f; unsigned short u; } cv; cv.f = h; return cv.u;
}

__device__ __forceinline__ uint4 pack8u16(const unsigned short* s) {
    uint4 v;
    v.x = (unsigned)s[0] | ((unsigned)s[1] << 16);
    v.y = (unsigned)s[2] | ((unsigned)s[3] << 16);
    v.z = (unsigned)s[4] | ((unsigned)s[5] << 16);
    v.w = (unsigned)s[6] | ((unsigned)s[7] << 16);
    return v;
}

// ---------------- setup: c2 (numpy pairwise) + f16 hi/lo B-frag tables ------
__device__ __forceinline__ float np_pairwise_sum64(const float* a) {
    float r[8];
#pragma unroll
    for (int j = 0; j < 8; ++j) r[j] = a[j];
#pragma unroll
    for (int i = 8; i < 64; i += 8) {
#pragma unroll
        for (int j = 0; j < 8; ++j) r[j] = __fadd_rn(r[j], a[i + j]);
    }
    return __fadd_rn(__fadd_rn(__fadd_rn(r[0], r[1]), __fadd_rn(r[2], r[3])),
                     __fadd_rn(__fadd_rn(r[4], r[5]), __fadd_rn(r[6], r[7])));
}

// B-frag tables in exact MFMA B-operand order (16x16x32: n=lane&15,
// k=(lane>>4)*8+j): element index ((T*2+kk)*64 + lane)*8 + j  maps to
// cb[T*16 + (lane&15)][kk*32 + (lane>>4)*8 + j].  (verified: R13-R16 absmax=0)
__global__ void vq_setup_kernel(const float* __restrict__ cb, float* __restrict__ c2,
                                unsigned short* __restrict__ bh,
                                unsigned short* __restrict__ bl, int buildT) {
    const int t = blockIdx.x * blockDim.x + threadIdx.x;   // 64 blocks x 64 = 4096
    if (buildT) {
        const int l    = t & 63;
        const int kkT  = t >> 6;                           // T*2+kk, 0..63
        const int code = (kkT >> 1) * 16 + (l & 15);
        const int d0   = (kkT & 1) * 32 + ((l >> 4) << 3);
        const float* crow = cb + code * CODE_DIM + d0;
        unsigned short hs[8], ls[8];
#pragma unroll
        for (int j = 0; j < 8; ++j) {
            const float c  = crow[j];
            const _Float16 h = (_Float16)c;                 // RNE
            const float lf = __fsub_rn(c, (float)h) * 4096.0f;  // exact (Sterbenz + pow2)
            hs[j] = f16_bits(h);
            ls[j] = f16_bits((_Float16)lf);                 // scaled lo: stays f16-normal
        }
        const uint4 hv = pack8u16(hs), lv = pack8u16(ls);
        *(uint4*)(bh + (size_t)t * 8) = hv;
        *(uint4*)(bl + (size_t)t * 8) = lv;
    }
    if (t < N_CODES) {
        const float* row = cb + t * CODE_DIM;
        float sq[CODE_DIM];
#pragma unroll
        for (int j = 0; j < CODE_DIM; ++j) sq[j] = __fmul_rn(row[j], row[j]);
        c2[t] = np_pairwise_sum64(sq);
    }
}

// Rare-path exact resolver — VERBATIM R12 arithmetic (bit-exact proven):
// reads only LDS (xs, s_x2e, s_res) and global (cb, c2). __noinline__, one
// hot call site; caller has no live register arrays across the call.
__device__ __noinline__ void resolve_cell(const float* __restrict__ cb,
                                          const float* __restrict__ c2g,
                                          const float* xs_base,      // &xs[0][0]
                                          const float* s_x2e,
                                          unsigned long long* s_res,
                                          int row, int k) {
    const float* crow = cb + (size_t)k * CODE_DIM;
    double b0 = 0.0, b1 = 0.0, b2 = 0.0, b3 = 0.0;
#pragma unroll
    for (int c = 0; c < CODE_DIM; c += 4) {
        b0 = fma((double)crow[c + 0], (double)xs_base[(c + 0) * XPITCH + row], b0);
        b1 = fma((double)crow[c + 1], (double)xs_base[(c + 1) * XPITCH + row], b1);
        b2 = fma((double)crow[c + 2], (double)xs_base[(c + 2) * XPITCH + row], b2);
        b3 = fma((double)crow[c + 3], (double)xs_base[(c + 3) * XPITCH + row], b3);
    }
    const double dot64 = (b0 + b1) + (b2 + b3);
    const float  ein   = (float)dot64;
    const float  tmp   = __fadd_rn(s_x2e[row], c2g[k]);
    const float  dk    = __fsub_rn(tmp, __fmul_rn(2.0f, ein));
    const unsigned u     = __float_as_uint(dk);
    const unsigned key32 = (u & 0x80000000u) ? ~u : (u | 0x80000000u);
    atomicMin(&s_res[row], ((unsigned long long)key32 << 32) | (unsigned)k);
}

// ---------------- main: 4-wave MFMA filter + exact resolve ------------------
// Block = one (b,h) group: 64 rows x 512 codes, 256 threads (4 waves).
// Wave wid: ALL 64 rows (4 M-tiles) x codes [wid*128, wid*128+128) (8 N-tiles).
__global__ __launch_bounds__(256, 2)
void vq_block_kernel(const float* __restrict__ in,
                     const float* __restrict__ cb,
                     const float* __restrict__ c2g,
                     const unsigned short* __restrict__ bhT,
                     const unsigned short* __restrict__ blT,
                     float* __restrict__ out) {
    __shared__ __align__(16) float xs[CODE_DIM][XPITCH];      // x-tile [dim][row], 17.4KB
    __shared__ __align__(16) unsigned short aHi[4][2][512];   // A-frags hi, 8KB
    __shared__ __align__(16) unsigned short aLo[4][2][512];   // A-frags lo, 8KB
    __shared__ float s_c2[N_CODES];                           // c2 staged, 2KB
    __shared__ float s_wm[4][64];                             // per-wave row mins
    __shared__ float s_lim[64];                               // block min + THR
    __shared__ float s_x2e[64];                               // numpy-exact x2 per row
    __shared__ int   s_cnt[64];                               // candidates per row
    __shared__ int   s_win[64];                               // sole candidate (cnt==1)
    __shared__ int   s_ncand;
    __shared__ int   s_cand[CAP];                             // packed (row<<16)|code
    __shared__ unsigned long long s_res[64];                  // packed (dk-key, k)

    const int tid  = threadIdx.x;
    const int lane = tid & 63;
    const int wid  = tid >> 6;               // 0..3
    const int gw   = blockIdx.x;             // (b,h) group 0..1023
    const float* src = in + (size_t)(gw >> 6) * B_STRIDE + (size_t)(gw & 63) * 64;

    // --- stage x-tile: xs[c][r] = src[c*4096 + r]; float4 slots, coalesced --
#pragma unroll
    for (int i = 0; i < 4; ++i) {
        const int s = tid + (i << 8);
        const int c = s >> 4, q = s & 15;
        *(float4*)&xs[c][q * 4] = *(const float4*)(src + (size_t)c * CH_STRIDE + q * 4);
    }
    // stage c2 into LDS (coalesced)
    s_c2[tid]       = c2g[tid];
    s_c2[tid + 256] = c2g[tid + 256];
    if (tid < 64) { s_cnt[tid] = 0; s_res[tid] = ~0ull; }
    if (tid == 0) s_ncand = 0;
    __syncthreads();

    // --- numpy-exact x2 per row (R5-proven rolling 8-acc pairwise order) ----
    if (tid < 64) {
        float r[8];
#pragma unroll
        for (int j = 0; j < 8; ++j) r[j] = __fmul_rn(xs[j][tid], xs[j][tid]);
#pragma unroll
        for (int i = 8; i < 64; i += 8) {
#pragma unroll
            for (int j = 0; j < 8; ++j)
                r[j] = __fadd_rn(r[j], __fmul_rn(xs[i + j][tid], xs[i + j][tid]));
        }
        s_x2e[tid] = __fadd_rn(
            __fadd_rn(__fadd_rn(r[0], r[1]), __fadd_rn(r[2], r[3])),
            __fadd_rn(__fadd_rn(r[4], r[5]), __fadd_rn(r[6], r[7])));
    }

    // --- shared A-frag build: ONCE per block (was per-wave, 4x redundant) ---
    // thread tid handles planes p = (tid>>6) and (tid>>6)+4; p -> (mt=p>>1,kk=p&1)
    // slot lane l = tid&63: row = mt*16+(l&15), d = kk*32+(l>>4)*8+j
    // (identical conversion + layout as R13's verified per-wave build)
#pragma unroll
    for (int pp = 0; pp < 2; ++pp) {
        const int p  = (tid >> 6) + (pp << 2);
        const int mt = p >> 1, kk = p & 1;
        const int l  = tid & 63;
        const int row = (mt << 4) + (l & 15);
        const int d0  = (kk << 5) + ((l >> 4) << 3);
        unsigned short hs[8], ls[8];
#pragma unroll
        for (int j = 0; j < 8; ++j) {
            const float x = xs[d0 + j][row];
            const _Float16 h = (_Float16)x;
            const float lf = __fsub_rn(x, (float)h) * 4096.0f;
            hs[j] = f16_bits(h);
            ls[j] = f16_bits((_Float16)lf);
        }
        *(uint4*)&aHi[mt][kk][l * 8] = pack8u16(hs);
        *(uint4*)&aLo[mt][kk][l * 8] = pack8u16(ls);
    }
    __syncthreads();

    // --- A-frags to registers: 16 conflict-free ds_read_b128 per thread -----
    f16x8 Ah[4][2], Al[4][2];
#pragma unroll
    for (int mt = 0; mt < 4; ++mt)
#pragma unroll
        for (int kk = 0; kk < 2; ++kk) {
            Ah[mt][kk] = *(const f16x8*)&aHi[mt][kk][lane * 8];
            Al[mt][kk] = *(const f16x8*)&aLo[mt][kk][lane * 8];
        }

    const int nsub  = lane & 15;
    const int rbase = (lane >> 4) << 2;      // row-in-tile base for D-layout

    // --- phase 1: full scan, row-min + per-tile min only --------------------
    float rm[16];                            // [mt*4+r] rows mt*16+rbase+r
#pragma unroll
    for (int i = 0; i < 16; ++i) rm[i] = 1e30f;
    float tmin[8];
#pragma unroll
    for (int t = 0; t < 8; ++t) {
        const int Tg = (wid << 3) + t;       // global N-tile 0..31
        const int T2 = Tg << 1;
        const f16x8 Bh0 = *(const f16x8*)(bhT + ((size_t)(T2 + 0) * 64 + lane) * 8);
        const f16x8 Bh1 = *(const f16x8*)(bhT + ((size_t)(T2 + 1) * 64 + lane) * 8);
        const f16x8 Bl0 = *(const f16x8*)(blT + ((size_t)(T2 + 0) * 64 + lane) * 8);
        const f16x8 Bl1 = *(const f16x8*)(blT + ((size_t)(T2 + 1) * 64 + lane) * 8);
        const float c2v = s_c2[(Tg << 4) + nsub];
        float tm = 1e30f;
#pragma unroll
        for (int mt = 0; mt < 4; ++mt) {
            f32x4 a1 = {0.f, 0.f, 0.f, 0.f};
            f32x4 a2 = {0.f, 0.f, 0.f, 0.f};
            a1 = __builtin_amdgcn_mfma_f32_16x16x32_f16(Ah[mt][0], Bh0, a1, 0, 0, 0);
            a1 = __builtin_amdgcn_mfma_f32_16x16x32_f16(Ah[mt][1], Bh1, a1, 0, 0, 0);
            a2 = __builtin_amdgcn_mfma_f32_16x16x32_f16(Al[mt][0], Bh0, a2, 0, 0, 0);
            a2 = __builtin_amdgcn_mfma_f32_16x16x32_f16(Ah[mt][0], Bl0, a2, 0, 0, 0);
            a2 = __builtin_amdgcn_mfma_f32_16x16x32_f16(Al[mt][1], Bh1, a2, 0, 0, 0);
            a2 = __builtin_amdgcn_mfma_f32_16x16x32_f16(Ah[mt][1], Bl1, a2, 0, 0, 0);
#pragma unroll
            for (int r = 0; r < 4; ++r) {
                const float d2 = __fmaf_rn(2.44140625e-4f, a2[r], a1[r]);  // +2^-12*lo
                const float v  = __fmaf_rn(-2.0f, d2, c2v);
                rm[(mt << 2) + r] = fminf(rm[(mt << 2) + r], v);
                tm = fminf(tm, v);
            }
        }
        tmin[t] = tm;
    }

    // --- row min over the 16 code-lanes of each group -----------------------
#pragma unroll
    for (int s = 1; s < 16; s <<= 1)
#pragma unroll
        for (int i = 0; i < 16; ++i) rm[i] = fminf(rm[i], __shfl_xor(rm[i], s, 64));
    if (nsub == 0) {
#pragma unroll
        for (int mt = 0; mt < 4; ++mt)
#pragma unroll
            for (int r = 0; r < 4; ++r)
                s_wm[wid][(mt << 4) + rbase + r] = rm[(mt << 2) + r];
    }
    __syncthreads();
    if (tid < 64) {
        float m = s_wm[0][tid];
#pragma unroll
        for (int w = 1; w < 4; ++w) m = fminf(m, s_wm[w][tid]);
        s_lim[tid] = m + THR;
    }
    __syncthreads();

    // lane-local lims for its 16 rows + their max (for the tile-skip ballot)
    float lim[16], lmax = -1e30f;
#pragma unroll
    for (int mt = 0; mt < 4; ++mt)
#pragma unroll
        for (int r = 0; r < 4; ++r) {
            const float L = s_lim[(mt << 4) + rbase + r];
            lim[(mt << 2) + r] = L;
            lmax = fmaxf(lmax, L);
        }

    // --- phase 2: recompute ONLY tiles that can contain candidates ----------
#pragma unroll
    for (int t = 0; t < 8; ++t) {
        if (__ballot(tmin[t] <= lmax) == 0ull) continue;   // wave-uniform skip
        const int Tg = (wid << 3) + t;
        const int T2 = Tg << 1;
        const f16x8 Bh0 = *(const f16x8*)(bhT + ((size_t)(T2 + 0) * 64 + lane) * 8);
        const f16x8 Bh1 = *(const f16x8*)(bhT + ((size_t)(T2 + 1) * 64 + lane) * 8);
        const f16x8 Bl0 = *(const f16x8*)(blT + ((size_t)(T2 + 0) * 64 + lane) * 8);
        const f16x8 Bl1 = *(const f16x8*)(blT + ((size_t)(T2 + 1) * 64 + lane) * 8);
        const float c2v = s_c2[(Tg << 4) + nsub];
#pragma unroll
        for (int mt = 0; mt < 4; ++mt) {
            f32x4 a1 = {0.f, 0.f, 0.f, 0.f};
            f32x4 a2 = {0.f, 0.f, 0.f, 0.f};
            a1 = __builtin_amdgcn_mfma_f32_16x16x32_f16(Ah[mt][0], Bh0, a1, 0, 0, 0);
            a1 = __builtin_amdgcn_mfma_f32_16x16x32_f16(Ah[mt][1], Bh1, a1, 0, 0, 0);
            a2 = __builtin_amdgcn_mfma_f32_16x16x32_f16(Al[mt][0], Bh0, a2, 0, 0, 0);
            a2 = __builtin_amdgcn_mfma_f32_16x16x32_f16(Ah[mt][0], Bl0, a2, 0, 0, 0);
            a2 = __builtin_amdgcn_mfma_f32_16x16x32_f16(Al[mt][1], Bh1, a2, 0, 0, 0);
            a2 = __builtin_amdgcn_mfma_f32_16x16x32_f16(Ah[mt][1], Bl1, a2, 0, 0, 0);
#pragma unroll
            for (int r = 0; r < 4; ++r) {
                const float d2 = __fmaf_rn(2.44140625e-4f, a2[r], a1[r]);
                const float v  = __fmaf_rn(-2.0f, d2, c2v);
                if (v <= lim[(mt << 2) + r]) {        // deterministic == phase-1
                    const int row  = (mt << 4) + rbase + r;
                    const int code = (Tg << 4) + nsub;
                    atomicAdd(&s_cnt[row], 1);
                    s_win[row] = code;                // sole writer iff cnt==1
                    const int slot = atomicAdd(&s_ncand, 1);
                    if (slot < CAP) s_cand[slot] = (row << 16) | code;
                }
            }
        }
    }
    __syncthreads();

    // --- resolve: ONE call site, thread-parallel over the candidate list ----
    const int nc = s_ncand;
    const int ne = nc < CAP ? nc : CAP;
    for (int e = tid; e < ne; e += 256) {
        const int row = s_cand[e] >> 16;
        const int k   = s_cand[e] & 0xFFFF;
        if (s_cnt[row] > 1)
            resolve_cell(cb, c2g, &xs[0][0], s_x2e, s_res, row, k);
    }
    if (nc > CAP) {                               // pathological-tie fallback
#pragma unroll 1
        for (int row = wid; row < 64; row += 4)
            if (s_cnt[row] > 1)
#pragma unroll 1
                for (int k = lane; k < N_CODES; k += 64)
                    resolve_cell(cb, c2g, &xs[0][0], s_x2e, s_res, row, k);
    }
    __syncthreads();

    // --- output: wave wid writes rows wid*16..+15 (coalesced 256B each) -----
    const size_t n0 = (size_t)gw * 64;
#pragma unroll
    for (int rr = 0; rr < 16; ++rr) {
        const int row = (wid << 4) + rr;
        const int idx = (s_cnt[row] == 1) ? s_win[row]
                                          : (int)(s_res[row] & 0xFFFFFFFFull);
        out[(n0 + row) * CODE_DIM + lane] = cb[(size_t)idx * CODE_DIM + lane];
    }
}

// ---------------- fallback (R9, proven 190us) if ws too small ---------------
__device__ __forceinline__ float exact_dk_fb(const float* __restrict__ cb,
                                             const float* __restrict__ c2,
                                             const float (&x)[CODE_DIM], float x2, int k) {
    const float* crow = cb + (size_t)k * CODE_DIM;
    double a0 = 0.0, a1 = 0.0, a2 = 0.0, a3 = 0.0;
#pragma unroll
    for (int j = 0; j < CODE_DIM; j += 4) {
        a0 = fma((double)crow[j + 0], (double)x[j + 0], a0);
        a1 = fma((double)crow[j + 1], (double)x[j + 1], a1);
        a2 = fma((double)crow[j + 2], (double)x[j + 2], a2);
        a3 = fma((double)crow[j + 3], (double)x[j + 3], a3);
    }
    const double dot = (a0 + a1) + (a2 + a3);
    const float  ein = (float)dot;
    return __fsub_rn(__fadd_rn(x2, c2[k]), __fmul_rn(2.0f, ein));
}

__global__ __launch_bounds__(512, 2)
void vq_fallback_kernel(const float* __restrict__ in, const float* __restrict__ cb,
                        const float* __restrict__ c2, float* __restrict__ out) {
    __shared__ float s_rb[8][64];
    __shared__ int   s_ri[8][64];
    const int tid = threadIdx.x, lane = tid & 63, wid = tid >> 6;
    const int gw = blockIdx.x, b = gw >> 6, h = gw & 63;
    const float* xin = in + (size_t)b * B_STRIDE + (size_t)h * 64 + lane;
    float x[CODE_DIM];
#pragma unroll
    for (int c = 0; c < CODE_DIM; ++c) x[c] = xin[(size_t)c * CH_STRIDE];
    float r[8];
#pragma unroll
    for (int j = 0; j < 8; ++j) r[j] = __fmul_rn(x[j], x[j]);
#pragma unroll
    for (int i = 8; i < 64; i += 8)
#pragma unroll
        for (int j = 0; j < 8; ++j) r[j] = __fadd_rn(r[j], __fmul_rn(x[i + j], x[i + j]));
    const float x2 = __fadd_rn(__fadd_rn(__fadd_rn(r[0], r[1]), __fadd_rn(r[2], r[3])),
                               __fadd_rn(__fadd_rn(r[4], r[5]), __fadd_rn(r[6], r[7])));
    const int k0 = __builtin_amdgcn_readfirstlane(wid) * 64;
    float ex_best = INFINITY; int bi = k0;
#pragma unroll 1
    for (int kk = 0; kk < 64; ++kk) {
        const float dk = exact_dk_fb(cb, c2, x, x2, k0 + kk);
        if (dk < ex_best) { ex_best = dk; bi = k0 + kk; }
    }
    s_rb[wid][lane] = ex_best; s_ri[wid][lane] = bi;
    __syncthreads();
    float fb2 = s_rb[0][lane]; int fi = s_ri[0][lane];
#pragma unroll
    for (int w = 1; w < 8; ++w) {
        if (s_rb[w][lane] < fb2) { fb2 = s_rb[w][lane]; fi = s_ri[w][lane]; }
    }
    const size_t n0 = (size_t)gw * 64;
#pragma unroll 1
    for (int rr = 0; rr < 8; ++rr) {
        const int row = wid * 8 + rr;
        const int idxr = __shfl(fi, row, 64);
        out[(n0 + row) * CODE_DIM + lane] = cb[(size_t)idxr * CODE_DIM + lane];
    }
}

extern "C" void kernel_launch(void* const* d_in, const int* in_sizes, int n_in,
                              void* d_out, int out_size, void* d_ws, size_t ws_size,
                              hipStream_t stream) {
    const float* in  = (const float*)d_in[0];   // (16,64,64,64) fp32
    const float* cb  = (const float*)d_in[1];   // (512,64) fp32
    float*       out = (float*)d_out;           // (16,64,64,64) fp32

    float* c2 = (float*)d_ws;                                    // 2 KB
    unsigned short* bh = (unsigned short*)((char*)d_ws + 2048);  // 64 KB f16-hi frags
    unsigned short* bl = (unsigned short*)((char*)d_ws + 2048 + 65536);  // 64 KB f16-lo
    const bool hasT = ws_size >= (size_t)(2048 + 2 * 65536);     // 133120 B

    vq_setup_kernel<<<dim3(64), dim3(64), 0, stream>>>(cb, c2, bh, bl, hasT ? 1 : 0);
    if (hasT) {
        // 1024 blocks = one (b,h) group (64 rows) each; 256 threads = 4 waves.
        vq_block_kernel<<<dim3(1024), dim3(256), 0, stream>>>(in, cb, c2, bh, bl, out);
    } else {
        vq_fallback_kernel<<<dim3(1024), dim3(512), 0, stream>>>(in, cb, c2, out);
    }
}

// Round 6
// 101.232 us; speedup vs baseline: 1.2894x; 1.1199x over previous
//
#include <hip/hip_runtime.h>
#include <math.h>

// VectorQuantizer — bit-exact emulation of the numpy fp32 reference (proven R2-R11):
//   d[n,k] = fl32( fl32(x2[n]+c2[k]) - fl32(2 * fl32(exact_fp64_dot)) ), first argmin.
//
// R18: hi-only MFMA filter + per-row adaptive threshold. R17's profile: MFMA
// busy 9.5us, VALU 12.5us, rest stalls at fixed 4 blocks/CU -> shrink the
// serial path. The f16-lo products only served filter accuracy; exactness
// needs THR >= 2*err, so drop them and widen THR per row with a PROVEN bound:
//   |v - (dk - x2)| <= 2^-10*(1/512)*Sum|x| + accum + ref-rounding
//                   <= 1.53e-5*sqrt(x2) + ~1.7e-5      (Sum|x| <= 8*sqrt(x2))
//   THR_row = 4e-5*sqrt(x2) + 1e-4   (>= 2.6x bound; extras ~0.1/row since
//   local d-spacing near min ~4.5e-3 >> 3e-4 window)
// Cuts: MFMA x1/3, B-loads x1/2, A-build/regs x1/2 (-32 VGPR), 3 VALU/elem,
// LDS -8KB. Two-phase deterministic skeleton + list resolver verbatim R15/R17.

#define N_CODES   512
#define CODE_DIM  64
#define CH_STRIDE 4096                      // floats between channels
#define B_STRIDE  (CODE_DIM * CH_STRIDE)    // floats between batches
#define XPITCH    68                        // xs row pitch (mult of 4)
#define CAP       256                       // candidate-list capacity

typedef _Float16 f16x8 __attribute__((ext_vector_type(8)));
typedef float    f32x4 __attribute__((ext_vector_type(4)));

__device__ __forceinline__ unsigned short f16_bits(_Float16 h) {
    union { _Float16 f; unsigned short u; } cv; cv.f = h; return cv.u;
}

__device__ __forceinline__ uint4 pack8u16(const unsigned short* s) {
    uint4 v;
    v.x = (unsigned)s[0] | ((unsigned)s[1] << 16);
    v.y = (unsigned)s[2] | ((unsigned)s[3] << 16);
    v.z = (unsigned)s[4] | ((unsigned)s[5] << 16);
    v.w = (unsigned)s[6] | ((unsigned)s[7] << 16);
    return v;
}

// ---------------- setup: c2 (numpy pairwise) + f16-hi B-frag table ----------
__device__ __forceinline__ float np_pairwise_sum64(const float* a) {
    float r[8];
#pragma unroll
    for (int j = 0; j < 8; ++j) r[j] = a[j];
#pragma unroll
    for (int i = 8; i < 64; i += 8) {
#pragma unroll
        for (int j = 0; j < 8; ++j) r[j] = __fadd_rn(r[j], a[i + j]);
    }
    return __fadd_rn(__fadd_rn(__fadd_rn(r[0], r[1]), __fadd_rn(r[2], r[3])),
                     __fadd_rn(__fadd_rn(r[4], r[5]), __fadd_rn(r[6], r[7])));
}

// B-frag table in exact MFMA B-operand order (16x16x32: n=lane&15,
// k=(lane>>4)*8+j): element index ((T*2+kk)*64 + lane)*8 + j  maps to
// cb[T*16 + (lane&15)][kk*32 + (lane>>4)*8 + j].  (verified: R13-R17 absmax=0)
__global__ void vq_setup_kernel(const float* __restrict__ cb, float* __restrict__ c2,
                                unsigned short* __restrict__ bh, int buildT) {
    const int t = blockIdx.x * blockDim.x + threadIdx.x;   // 64 blocks x 64 = 4096
    if (buildT) {
        const int l    = t & 63;
        const int kkT  = t >> 6;                           // T*2+kk, 0..63
        const int code = (kkT >> 1) * 16 + (l & 15);
        const int d0   = (kkT & 1) * 32 + ((l >> 4) << 3);
        const float* crow = cb + code * CODE_DIM + d0;
        unsigned short hs[8];
#pragma unroll
        for (int j = 0; j < 8; ++j) hs[j] = f16_bits((_Float16)crow[j]);   // RNE
        *(uint4*)(bh + (size_t)t * 8) = pack8u16(hs);
    }
    if (t < N_CODES) {
        const float* row = cb + t * CODE_DIM;
        float sq[CODE_DIM];
#pragma unroll
        for (int j = 0; j < CODE_DIM; ++j) sq[j] = __fmul_rn(row[j], row[j]);
        c2[t] = np_pairwise_sum64(sq);
    }
}

// Rare-path exact resolver — VERBATIM R12 arithmetic (bit-exact proven):
// reads only LDS (xs, s_x2e, s_res) and global (cb, c2). __noinline__, one
// hot call site; caller has no live register arrays across the call.
__device__ __noinline__ void resolve_cell(const float* __restrict__ cb,
                                          const float* __restrict__ c2g,
                                          const float* xs_base,      // &xs[0][0]
                                          const float* s_x2e,
                                          unsigned long long* s_res,
                                          int row, int k) {
    const float* crow = cb + (size_t)k * CODE_DIM;
    double b0 = 0.0, b1 = 0.0, b2 = 0.0, b3 = 0.0;
#pragma unroll
    for (int c = 0; c < CODE_DIM; c += 4) {
        b0 = fma((double)crow[c + 0], (double)xs_base[(c + 0) * XPITCH + row], b0);
        b1 = fma((double)crow[c + 1], (double)xs_base[(c + 1) * XPITCH + row], b1);
        b2 = fma((double)crow[c + 2], (double)xs_base[(c + 2) * XPITCH + row], b2);
        b3 = fma((double)crow[c + 3], (double)xs_base[(c + 3) * XPITCH + row], b3);
    }
    const double dot64 = (b0 + b1) + (b2 + b3);
    const float  ein   = (float)dot64;
    const float  tmp   = __fadd_rn(s_x2e[row], c2g[k]);
    const float  dk    = __fsub_rn(tmp, __fmul_rn(2.0f, ein));
    const unsigned u     = __float_as_uint(dk);
    const unsigned key32 = (u & 0x80000000u) ? ~u : (u | 0x80000000u);
    atomicMin(&s_res[row], ((unsigned long long)key32 << 32) | (unsigned)k);
}

// ---------------- main: 4-wave hi-only MFMA filter + exact resolve ----------
// Block = one (b,h) group: 64 rows x 512 codes, 256 threads (4 waves).
// Wave wid: ALL 64 rows (4 M-tiles) x codes [wid*128, wid*128+128) (8 N-tiles).
__global__ __launch_bounds__(256, 2)
void vq_block_kernel(const float* __restrict__ in,
                     const float* __restrict__ cb,
                     const float* __restrict__ c2g,
                     const unsigned short* __restrict__ bhT,
                     float* __restrict__ out) {
    __shared__ __align__(16) float xs[CODE_DIM][XPITCH];      // x-tile [dim][row], 17.4KB
    __shared__ __align__(16) unsigned short aHi[4][2][512];   // A-frags hi, 8KB
    __shared__ float s_c2[N_CODES];                           // c2 staged, 2KB
    __shared__ float s_wm[4][64];                             // per-wave row mins
    __shared__ float s_lim[64];                               // row min + THR_row
    __shared__ float s_x2e[64];                               // numpy-exact x2 per row
    __shared__ int   s_cnt[64];                               // candidates per row
    __shared__ int   s_win[64];                               // sole candidate (cnt==1)
    __shared__ int   s_ncand;
    __shared__ int   s_cand[CAP];                             // packed (row<<16)|code
    __shared__ unsigned long long s_res[64];                  // packed (dk-key, k)

    const int tid  = threadIdx.x;
    const int lane = tid & 63;
    const int wid  = tid >> 6;               // 0..3
    const int gw   = blockIdx.x;             // (b,h) group 0..1023
    const float* src = in + (size_t)(gw >> 6) * B_STRIDE + (size_t)(gw & 63) * 64;

    // --- stage x-tile: xs[c][r] = src[c*4096 + r]; float4 slots, coalesced --
#pragma unroll
    for (int i = 0; i < 4; ++i) {
        const int s = tid + (i << 8);
        const int c = s >> 4, q = s & 15;
        *(float4*)&xs[c][q * 4] = *(const float4*)(src + (size_t)c * CH_STRIDE + q * 4);
    }
    // stage c2 into LDS (coalesced)
    s_c2[tid]       = c2g[tid];
    s_c2[tid + 256] = c2g[tid + 256];
    if (tid < 64) { s_cnt[tid] = 0; s_res[tid] = ~0ull; }
    if (tid == 0) s_ncand = 0;
    __syncthreads();

    // --- numpy-exact x2 per row (R5-proven rolling 8-acc pairwise order) ----
    if (tid < 64) {
        float r[8];
#pragma unroll
        for (int j = 0; j < 8; ++j) r[j] = __fmul_rn(xs[j][tid], xs[j][tid]);
#pragma unroll
        for (int i = 8; i < 64; i += 8) {
#pragma unroll
            for (int j = 0; j < 8; ++j)
                r[j] = __fadd_rn(r[j], __fmul_rn(xs[i + j][tid], xs[i + j][tid]));
        }
        s_x2e[tid] = __fadd_rn(
            __fadd_rn(__fadd_rn(r[0], r[1]), __fadd_rn(r[2], r[3])),
            __fadd_rn(__fadd_rn(r[4], r[5]), __fadd_rn(r[6], r[7])));
    }

    // --- shared A-frag build (hi only): once per block, 8 planes / 256 thr --
    // plane p = tid>>6 .. +4: (mt=p>>1, kk=p&1); slot l=tid&63:
    // row = mt*16+(l&15), d = kk*32+(l>>4)*8+j   (R13-verified layout)
#pragma unroll
    for (int pp = 0; pp < 2; ++pp) {
        const int p  = (tid >> 6) + (pp << 2);
        const int mt = p >> 1, kk = p & 1;
        const int l  = tid & 63;
        const int row = (mt << 4) + (l & 15);
        const int d0  = (kk << 5) + ((l >> 4) << 3);
        unsigned short hs[8];
#pragma unroll
        for (int j = 0; j < 8; ++j)
            hs[j] = f16_bits((_Float16)xs[d0 + j][row]);
        *(uint4*)&aHi[mt][kk][l * 8] = pack8u16(hs);
    }
    __syncthreads();

    // --- A-frags to registers: 8 conflict-free ds_read_b128 per thread ------
    f16x8 Ah[4][2];
#pragma unroll
    for (int mt = 0; mt < 4; ++mt)
#pragma unroll
        for (int kk = 0; kk < 2; ++kk)
            Ah[mt][kk] = *(const f16x8*)&aHi[mt][kk][lane * 8];

    const int nsub  = lane & 15;
    const int rbase = (lane >> 4) << 2;      // row-in-tile base for D-layout

    // --- phase 1: full scan, row-min + per-tile min only --------------------
    float rm[16];                            // [mt*4+r] rows mt*16+rbase+r
#pragma unroll
    for (int i = 0; i < 16; ++i) rm[i] = 1e30f;
    float tmin[8];
#pragma unroll
    for (int t = 0; t < 8; ++t) {
        const int Tg = (wid << 3) + t;       // global N-tile 0..31
        const int T2 = Tg << 1;
        const f16x8 Bh0 = *(const f16x8*)(bhT + ((size_t)(T2 + 0) * 64 + lane) * 8);
        const f16x8 Bh1 = *(const f16x8*)(bhT + ((size_t)(T2 + 1) * 64 + lane) * 8);
        const float c2v = s_c2[(Tg << 4) + nsub];
        float tm = 1e30f;
#pragma unroll
        for (int mt = 0; mt < 4; ++mt) {
            f32x4 a1 = {0.f, 0.f, 0.f, 0.f};
            a1 = __builtin_amdgcn_mfma_f32_16x16x32_f16(Ah[mt][0], Bh0, a1, 0, 0, 0);
            a1 = __builtin_amdgcn_mfma_f32_16x16x32_f16(Ah[mt][1], Bh1, a1, 0, 0, 0);
#pragma unroll
            for (int r = 0; r < 4; ++r) {
                const float v = __fmaf_rn(-2.0f, a1[r], c2v);
                rm[(mt << 2) + r] = fminf(rm[(mt << 2) + r], v);
                tm = fminf(tm, v);
            }
        }
        tmin[t] = tm;
    }

    // --- row min over the 16 code-lanes of each group -----------------------
#pragma unroll
    for (int s = 1; s < 16; s <<= 1)
#pragma unroll
        for (int i = 0; i < 16; ++i) rm[i] = fminf(rm[i], __shfl_xor(rm[i], s, 64));
    if (nsub == 0) {
#pragma unroll
        for (int mt = 0; mt < 4; ++mt)
#pragma unroll
            for (int r = 0; r < 4; ++r)
                s_wm[wid][(mt << 4) + rbase + r] = rm[(mt << 2) + r];
    }
    __syncthreads();
    if (tid < 64) {
        float m = s_wm[0][tid];
#pragma unroll
        for (int w = 1; w < 4; ++w) m = fminf(m, s_wm[w][tid]);
        // per-row adaptive threshold: 2*err bound (err <= 1.53e-5*sqrt(x2)
        // + ~1.7e-5) with >=2.6x margin. Exact-argmin provably in window.
        s_lim[tid] = m + (4.0e-5f * sqrtf(s_x2e[tid]) + 1.0e-4f);
    }
    __syncthreads();

    // lane-local lims for its 16 rows + their max (for the tile-skip ballot)
    float lim[16], lmax = -1e30f;
#pragma unroll
    for (int mt = 0; mt < 4; ++mt)
#pragma unroll
        for (int r = 0; r < 4; ++r) {
            const float L = s_lim[(mt << 4) + rbase + r];
            lim[(mt << 2) + r] = L;
            lmax = fmaxf(lmax, L);
        }

    // --- phase 2: recompute ONLY tiles that can contain candidates ----------
#pragma unroll
    for (int t = 0; t < 8; ++t) {
        if (__ballot(tmin[t] <= lmax) == 0ull) continue;   // wave-uniform skip
        const int Tg = (wid << 3) + t;
        const int T2 = Tg << 1;
        const f16x8 Bh0 = *(const f16x8*)(bhT + ((size_t)(T2 + 0) * 64 + lane) * 8);
        const f16x8 Bh1 = *(const f16x8*)(bhT + ((size_t)(T2 + 1) * 64 + lane) * 8);
        const float c2v = s_c2[(Tg << 4) + nsub];
#pragma unroll
        for (int mt = 0; mt < 4; ++mt) {
            f32x4 a1 = {0.f, 0.f, 0.f, 0.f};
            a1 = __builtin_amdgcn_mfma_f32_16x16x32_f16(Ah[mt][0], Bh0, a1, 0, 0, 0);
            a1 = __builtin_amdgcn_mfma_f32_16x16x32_f16(Ah[mt][1], Bh1, a1, 0, 0, 0);
#pragma unroll
            for (int r = 0; r < 4; ++r) {
                const float v = __fmaf_rn(-2.0f, a1[r], c2v);
                if (v <= lim[(mt << 2) + r]) {        // deterministic == phase-1
                    const int row  = (mt << 4) + rbase + r;
                    const int code = (Tg << 4) + nsub;
                    atomicAdd(&s_cnt[row], 1);
                    s_win[row] = code;                // sole writer iff cnt==1
                    const int slot = atomicAdd(&s_ncand, 1);
                    if (slot < CAP) s_cand[slot] = (row << 16) | code;
                }
            }
        }
    }
    __syncthreads();

    // --- resolve: ONE call site, thread-parallel over the candidate list ----
    const int nc = s_ncand;
    const int ne = nc < CAP ? nc : CAP;
    for (int e = tid; e < ne; e += 256) {
        const int row = s_cand[e] >> 16;
        const int k   = s_cand[e] & 0xFFFF;
        if (s_cnt[row] > 1)
            resolve_cell(cb, c2g, &xs[0][0], s_x2e, s_res, row, k);
    }
    if (nc > CAP) {                               // pathological-tie fallback
#pragma unroll 1
        for (int row = wid; row < 64; row += 4)
            if (s_cnt[row] > 1)
#pragma unroll 1
                for (int k = lane; k < N_CODES; k += 64)
                    resolve_cell(cb, c2g, &xs[0][0], s_x2e, s_res, row, k);
    }
    __syncthreads();

    // --- output: wave wid writes rows wid*16..+15 (coalesced 256B each) -----
    const size_t n0 = (size_t)gw * 64;
#pragma unroll
    for (int rr = 0; rr < 16; ++rr) {
        const int row = (wid << 4) + rr;
        const int idx = (s_cnt[row] == 1) ? s_win[row]
                                          : (int)(s_res[row] & 0xFFFFFFFFull);
        out[(n0 + row) * CODE_DIM + lane] = cb[(size_t)idx * CODE_DIM + lane];
    }
}

// ---------------- fallback (R9, proven 190us) if ws too small ---------------
__device__ __forceinline__ float exact_dk_fb(const float* __restrict__ cb,
                                             const float* __restrict__ c2,
                                             const float (&x)[CODE_DIM], float x2, int k) {
    const float* crow = cb + (size_t)k * CODE_DIM;
    double a0 = 0.0, a1 = 0.0, a2 = 0.0, a3 = 0.0;
#pragma unroll
    for (int j = 0; j < CODE_DIM; j += 4) {
        a0 = fma((double)crow[j + 0], (double)x[j + 0], a0);
        a1 = fma((double)crow[j + 1], (double)x[j + 1], a1);
        a2 = fma((double)crow[j + 2], (double)x[j + 2], a2);
        a3 = fma((double)crow[j + 3], (double)x[j + 3], a3);
    }
    const double dot = (a0 + a1) + (a2 + a3);
    const float  ein = (float)dot;
    return __fsub_rn(__fadd_rn(x2, c2[k]), __fmul_rn(2.0f, ein));
}

__global__ __launch_bounds__(512, 2)
void vq_fallback_kernel(const float* __restrict__ in, const float* __restrict__ cb,
                        const float* __restrict__ c2, float* __restrict__ out) {
    __shared__ float s_rb[8][64];
    __shared__ int   s_ri[8][64];
    const int tid = threadIdx.x, lane = tid & 63, wid = tid >> 6;
    const int gw = blockIdx.x, b = gw >> 6, h = gw & 63;
    const float* xin = in + (size_t)b * B_STRIDE + (size_t)h * 64 + lane;
    float x[CODE_DIM];
#pragma unroll
    for (int c = 0; c < CODE_DIM; ++c) x[c] = xin[(size_t)c * CH_STRIDE];
    float r[8];
#pragma unroll
    for (int j = 0; j < 8; ++j) r[j] = __fmul_rn(x[j], x[j]);
#pragma unroll
    for (int i = 8; i < 64; i += 8)
#pragma unroll
        for (int j = 0; j < 8; ++j) r[j] = __fadd_rn(r[j], __fmul_rn(x[i + j], x[i + j]));
    const float x2 = __fadd_rn(__fadd_rn(__fadd_rn(r[0], r[1]), __fadd_rn(r[2], r[3])),
                               __fadd_rn(__fadd_rn(r[4], r[5]), __fadd_rn(r[6], r[7])));
    const int k0 = __builtin_amdgcn_readfirstlane(wid) * 64;
    float ex_best = INFINITY; int bi = k0;
#pragma unroll 1
    for (int kk = 0; kk < 64; ++kk) {
        const float dk = exact_dk_fb(cb, c2, x, x2, k0 + kk);
        if (dk < ex_best) { ex_best = dk; bi = k0 + kk; }
    }
    s_rb[wid][lane] = ex_best; s_ri[wid][lane] = bi;
    __syncthreads();
    float fb2 = s_rb[0][lane]; int fi = s_ri[0][lane];
#pragma unroll
    for (int w = 1; w < 8; ++w) {
        if (s_rb[w][lane] < fb2) { fb2 = s_rb[w][lane]; fi = s_ri[w][lane]; }
    }
    const size_t n0 = (size_t)gw * 64;
#pragma unroll 1
    for (int rr = 0; rr < 8; ++rr) {
        const int row = wid * 8 + rr;
        const int idxr = __shfl(fi, row, 64);
        out[(n0 + row) * CODE_DIM + lane] = cb[(size_t)idxr * CODE_DIM + lane];
    }
}

extern "C" void kernel_launch(void* const* d_in, const int* in_sizes, int n_in,
                              void* d_out, int out_size, void* d_ws, size_t ws_size,
                              hipStream_t stream) {
    const float* in  = (const float*)d_in[0];   // (16,64,64,64) fp32
    const float* cb  = (const float*)d_in[1];   // (512,64) fp32
    float*       out = (float*)d_out;           // (16,64,64,64) fp32

    float* c2 = (float*)d_ws;                                    // 2 KB
    unsigned short* bh = (unsigned short*)((char*)d_ws + 2048);  // 64 KB f16-hi frags
    const bool hasT = ws_size >= (size_t)(2048 + 65536);         // 66.5 KB

    vq_setup_kernel<<<dim3(64), dim3(64), 0, stream>>>(cb, c2, bh, hasT ? 1 : 0);
    if (hasT) {
        // 1024 blocks = one (b,h) group (64 rows) each; 256 threads = 4 waves.
        vq_block_kernel<<<dim3(1024), dim3(256), 0, stream>>>(in, cb, c2, bh, out);
    } else {
        vq_fallback_kernel<<<dim3(1024), dim3(512), 0, stream>>>(in, cb, c2, out);
    }
}

// Round 7
// 98.753 us; speedup vs baseline: 1.3218x; 1.0251x over previous
//
#include <hip/hip_runtime.h>
#include <math.h>

// VectorQuantizer — bit-exact emulation of the numpy fp32 reference (proven R2-R11):
//   d[n,k] = fl32( fl32(x2[n]+c2[k]) - fl32(2 * fl32(exact_fp64_dot)) ), first argmin.
//
// R19: critical-path cut. R18's kernel is single-block-latency-bound (1024
// blocks on 256 CUs all co-resident; pipes <25% busy). Three changes, no
// numerics touched:
//   * B hi-frags prefetched to REGISTERS at kernel top (depend only on
//     global bhT): L2 latency hides under x-staging + A-build; phase 1 is
//     load-free; phase 2 reuses in-reg B (zero reloads, bit-identical
//     recompute preserved).
//   * tmin/ballot tile-skip dropped: it skipped ~13% of tiles for +1 fmin
//     per element (128 VALU/wave) + 8 VGPR. Net negative.
//   * THR_row folded into the x2 phase (s_thr), lim-combine = 3 fmin + add.
// Skeleton, A-build, candidate list, fp64 resolver, adaptive THR (proof in
// R18 header), output: verbatim R18 (absmax=0 proven).

#define N_CODES   512
#define CODE_DIM  64
#define CH_STRIDE 4096                      // floats between channels
#define B_STRIDE  (CODE_DIM * CH_STRIDE)    // floats between batches
#define XPITCH    68                        // xs row pitch (mult of 4)
#define CAP       256                       // candidate-list capacity

typedef _Float16 f16x8 __attribute__((ext_vector_type(8)));
typedef float    f32x4 __attribute__((ext_vector_type(4)));

__device__ __forceinline__ unsigned short f16_bits(_Float16 h) {
    union { _Float16 f; unsigned short u; } cv; cv.f = h; return cv.u;
}

__device__ __forceinline__ uint4 pack8u16(const unsigned short* s) {
    uint4 v;
    v.x = (unsigned)s[0] | ((unsigned)s[1] << 16);
    v.y = (unsigned)s[2] | ((unsigned)s[3] << 16);
    v.z = (unsigned)s[4] | ((unsigned)s[5] << 16);
    v.w = (unsigned)s[6] | ((unsigned)s[7] << 16);
    return v;
}

// ---------------- setup: c2 (numpy pairwise) + f16-hi B-frag table ----------
__device__ __forceinline__ float np_pairwise_sum64(const float* a) {
    float r[8];
#pragma unroll
    for (int j = 0; j < 8; ++j) r[j] = a[j];
#pragma unroll
    for (int i = 8; i < 64; i += 8) {
#pragma unroll
        for (int j = 0; j < 8; ++j) r[j] = __fadd_rn(r[j], a[i + j]);
    }
    return __fadd_rn(__fadd_rn(__fadd_rn(r[0], r[1]), __fadd_rn(r[2], r[3])),
                     __fadd_rn(__fadd_rn(r[4], r[5]), __fadd_rn(r[6], r[7])));
}

// B-frag table in exact MFMA B-operand order (16x16x32: n=lane&15,
// k=(lane>>4)*8+j): element index ((T*2+kk)*64 + lane)*8 + j  maps to
// cb[T*16 + (lane&15)][kk*32 + (lane>>4)*8 + j].  (verified: R13-R18 absmax=0)
__global__ void vq_setup_kernel(const float* __restrict__ cb, float* __restrict__ c2,
                                unsigned short* __restrict__ bh, int buildT) {
    const int t = blockIdx.x * blockDim.x + threadIdx.x;   // 64 blocks x 64 = 4096
    if (buildT) {
        const int l    = t & 63;
        const int kkT  = t >> 6;                           // T*2+kk, 0..63
        const int code = (kkT >> 1) * 16 + (l & 15);
        const int d0   = (kkT & 1) * 32 + ((l >> 4) << 3);
        const float* crow = cb + code * CODE_DIM + d0;
        unsigned short hs[8];
#pragma unroll
        for (int j = 0; j < 8; ++j) hs[j] = f16_bits((_Float16)crow[j]);   // RNE
        *(uint4*)(bh + (size_t)t * 8) = pack8u16(hs);
    }
    if (t < N_CODES) {
        const float* row = cb + t * CODE_DIM;
        float sq[CODE_DIM];
#pragma unroll
        for (int j = 0; j < CODE_DIM; ++j) sq[j] = __fmul_rn(row[j], row[j]);
        c2[t] = np_pairwise_sum64(sq);
    }
}

// Rare-path exact resolver — VERBATIM R12 arithmetic (bit-exact proven):
// reads only LDS (xs, s_x2e, s_res) and global (cb, c2). __noinline__, one
// hot call site; caller has no live register arrays across the call.
__device__ __noinline__ void resolve_cell(const float* __restrict__ cb,
                                          const float* __restrict__ c2g,
                                          const float* xs_base,      // &xs[0][0]
                                          const float* s_x2e,
                                          unsigned long long* s_res,
                                          int row, int k) {
    const float* crow = cb + (size_t)k * CODE_DIM;
    double b0 = 0.0, b1 = 0.0, b2 = 0.0, b3 = 0.0;
#pragma unroll
    for (int c = 0; c < CODE_DIM; c += 4) {
        b0 = fma((double)crow[c + 0], (double)xs_base[(c + 0) * XPITCH + row], b0);
        b1 = fma((double)crow[c + 1], (double)xs_base[(c + 1) * XPITCH + row], b1);
        b2 = fma((double)crow[c + 2], (double)xs_base[(c + 2) * XPITCH + row], b2);
        b3 = fma((double)crow[c + 3], (double)xs_base[(c + 3) * XPITCH + row], b3);
    }
    const double dot64 = (b0 + b1) + (b2 + b3);
    const float  ein   = (float)dot64;
    const float  tmp   = __fadd_rn(s_x2e[row], c2g[k]);
    const float  dk    = __fsub_rn(tmp, __fmul_rn(2.0f, ein));
    const unsigned u     = __float_as_uint(dk);
    const unsigned key32 = (u & 0x80000000u) ? ~u : (u | 0x80000000u);
    atomicMin(&s_res[row], ((unsigned long long)key32 << 32) | (unsigned)k);
}

// ---------------- main: 4-wave hi-only MFMA filter + exact resolve ----------
// Block = one (b,h) group: 64 rows x 512 codes, 256 threads (4 waves).
// Wave wid: ALL 64 rows (4 M-tiles) x codes [wid*128, wid*128+128) (8 N-tiles).
__global__ __launch_bounds__(256, 2)
void vq_block_kernel(const float* __restrict__ in,
                     const float* __restrict__ cb,
                     const float* __restrict__ c2g,
                     const unsigned short* __restrict__ bhT,
                     float* __restrict__ out) {
    __shared__ __align__(16) float xs[CODE_DIM][XPITCH];      // x-tile [dim][row], 17.4KB
    __shared__ __align__(16) unsigned short aHi[4][2][512];   // A-frags hi, 8KB
    __shared__ float s_c2[N_CODES];                           // c2 staged, 2KB
    __shared__ float s_wm[4][64];                             // per-wave row mins
    __shared__ float s_lim[64];                               // row min + THR_row
    __shared__ float s_thr[64];                               // 4e-5*sqrt(x2)+1e-4
    __shared__ float s_x2e[64];                               // numpy-exact x2 per row
    __shared__ int   s_cnt[64];                               // candidates per row
    __shared__ int   s_win[64];                               // sole candidate (cnt==1)
    __shared__ int   s_ncand;
    __shared__ int   s_cand[CAP];                             // packed (row<<16)|code
    __shared__ unsigned long long s_res[64];                  // packed (dk-key, k)

    const int tid  = threadIdx.x;
    const int lane = tid & 63;
    const int wid  = tid >> 6;               // 0..3
    const int gw   = blockIdx.x;             // (b,h) group 0..1023
    const float* src = in + (size_t)(gw >> 6) * B_STRIDE + (size_t)(gw & 63) * 64;

    // --- B prefetch: all 16 hi-frags for this wave's 8 N-tiles, to REGISTERS.
    //     Independent of LDS -> L2 latency hides under staging + A-build; the
    //     SAME registers serve phase 1 and phase 2 (no reloads).
    f16x8 Bh[8][2];
#pragma unroll
    for (int t = 0; t < 8; ++t) {
        const int T2 = (((wid << 3) + t) << 1);
        Bh[t][0] = *(const f16x8*)(bhT + ((size_t)(T2 + 0) * 64 + lane) * 8);
        Bh[t][1] = *(const f16x8*)(bhT + ((size_t)(T2 + 1) * 64 + lane) * 8);
    }

    // --- stage x-tile: xs[c][r] = src[c*4096 + r]; float4 slots, coalesced --
#pragma unroll
    for (int i = 0; i < 4; ++i) {
        const int s = tid + (i << 8);
        const int c = s >> 4, q = s & 15;
        *(float4*)&xs[c][q * 4] = *(const float4*)(src + (size_t)c * CH_STRIDE + q * 4);
    }
    // stage c2 into LDS (coalesced)
    s_c2[tid]       = c2g[tid];
    s_c2[tid + 256] = c2g[tid + 256];
    if (tid < 64) { s_cnt[tid] = 0; s_res[tid] = ~0ull; }
    if (tid == 0) s_ncand = 0;
    __syncthreads();

    // --- numpy-exact x2 per row (R5-proven order) + per-row THR -------------
    if (tid < 64) {
        float r[8];
#pragma unroll
        for (int j = 0; j < 8; ++j) r[j] = __fmul_rn(xs[j][tid], xs[j][tid]);
#pragma unroll
        for (int i = 8; i < 64; i += 8) {
#pragma unroll
            for (int j = 0; j < 8; ++j)
                r[j] = __fadd_rn(r[j], __fmul_rn(xs[i + j][tid], xs[i + j][tid]));
        }
        const float x2 = __fadd_rn(
            __fadd_rn(__fadd_rn(r[0], r[1]), __fadd_rn(r[2], r[3])),
            __fadd_rn(__fadd_rn(r[4], r[5]), __fadd_rn(r[6], r[7])));
        s_x2e[tid] = x2;
        // per-row adaptive threshold: 2*err bound (err <= 1.53e-5*sqrt(x2)
        // + ~1.7e-5) with >=2.6x margin (R18-proven, absmax=0).
        s_thr[tid] = __fmaf_rn(4.0e-5f, sqrtf(x2), 1.0e-4f);
    }

    // --- shared A-frag build (hi only): once per block, 8 planes / 256 thr --
    // plane p = tid>>6 .. +4: (mt=p>>1, kk=p&1); slot l=tid&63:
    // row = mt*16+(l&15), d = kk*32+(l>>4)*8+j   (R13-verified layout)
#pragma unroll
    for (int pp = 0; pp < 2; ++pp) {
        const int p  = (tid >> 6) + (pp << 2);
        const int mt = p >> 1, kk = p & 1;
        const int l  = tid & 63;
        const int row = (mt << 4) + (l & 15);
        const int d0  = (kk << 5) + ((l >> 4) << 3);
        unsigned short hs[8];
#pragma unroll
        for (int j = 0; j < 8; ++j)
            hs[j] = f16_bits((_Float16)xs[d0 + j][row]);
        *(uint4*)&aHi[mt][kk][l * 8] = pack8u16(hs);
    }
    __syncthreads();

    // --- A-frags to registers: 8 conflict-free ds_read_b128 per thread ------
    f16x8 Ah[4][2];
#pragma unroll
    for (int mt = 0; mt < 4; ++mt)
#pragma unroll
        for (int kk = 0; kk < 2; ++kk)
            Ah[mt][kk] = *(const f16x8*)&aHi[mt][kk][lane * 8];

    const int nsub  = lane & 15;
    const int rbase = (lane >> 4) << 2;      // row-in-tile base for D-layout

    // --- phase 1: full scan, row-min only (load-free: B in registers) -------
    float rm[16];                            // [mt*4+r] rows mt*16+rbase+r
#pragma unroll
    for (int i = 0; i < 16; ++i) rm[i] = 1e30f;
#pragma unroll
    for (int t = 0; t < 8; ++t) {
        const float c2v = s_c2[((((wid << 3) + t)) << 4) + nsub];
#pragma unroll
        for (int mt = 0; mt < 4; ++mt) {
            f32x4 a1 = {0.f, 0.f, 0.f, 0.f};
            a1 = __builtin_amdgcn_mfma_f32_16x16x32_f16(Ah[mt][0], Bh[t][0], a1, 0, 0, 0);
            a1 = __builtin_amdgcn_mfma_f32_16x16x32_f16(Ah[mt][1], Bh[t][1], a1, 0, 0, 0);
#pragma unroll
            for (int r = 0; r < 4; ++r) {
                const float v = __fmaf_rn(-2.0f, a1[r], c2v);
                rm[(mt << 2) + r] = fminf(rm[(mt << 2) + r], v);
            }
        }
    }

    // --- row min over the 16 code-lanes of each group -----------------------
#pragma unroll
    for (int s = 1; s < 16; s <<= 1)
#pragma unroll
        for (int i = 0; i < 16; ++i) rm[i] = fminf(rm[i], __shfl_xor(rm[i], s, 64));
    if (nsub == 0) {
#pragma unroll
        for (int mt = 0; mt < 4; ++mt)
#pragma unroll
            for (int r = 0; r < 4; ++r)
                s_wm[wid][(mt << 4) + rbase + r] = rm[(mt << 2) + r];
    }
    __syncthreads();
    if (tid < 64) {
        float m = s_wm[0][tid];
#pragma unroll
        for (int w = 1; w < 4; ++w) m = fminf(m, s_wm[w][tid]);
        s_lim[tid] = m + s_thr[tid];
    }
    __syncthreads();

    // lane-local lims for its 16 rows
    float lim[16];
#pragma unroll
    for (int mt = 0; mt < 4; ++mt)
#pragma unroll
        for (int r = 0; r < 4; ++r)
            lim[(mt << 2) + r] = s_lim[(mt << 4) + rbase + r];

    // --- phase 2: bit-identical recompute from in-reg B, collect candidates -
#pragma unroll
    for (int t = 0; t < 8; ++t) {
        const int Tg = (wid << 3) + t;
        const float c2v = s_c2[(Tg << 4) + nsub];
#pragma unroll
        for (int mt = 0; mt < 4; ++mt) {
            f32x4 a1 = {0.f, 0.f, 0.f, 0.f};
            a1 = __builtin_amdgcn_mfma_f32_16x16x32_f16(Ah[mt][0], Bh[t][0], a1, 0, 0, 0);
            a1 = __builtin_amdgcn_mfma_f32_16x16x32_f16(Ah[mt][1], Bh[t][1], a1, 0, 0, 0);
#pragma unroll
            for (int r = 0; r < 4; ++r) {
                const float v = __fmaf_rn(-2.0f, a1[r], c2v);
                if (v <= lim[(mt << 2) + r]) {        // deterministic == phase-1
                    const int row  = (mt << 4) + rbase + r;
                    const int code = (Tg << 4) + nsub;
                    atomicAdd(&s_cnt[row], 1);
                    s_win[row] = code;                // sole writer iff cnt==1
                    const int slot = atomicAdd(&s_ncand, 1);
                    if (slot < CAP) s_cand[slot] = (row << 16) | code;
                }
            }
        }
    }
    __syncthreads();

    // --- resolve: ONE call site, thread-parallel over the candidate list ----
    const int nc = s_ncand;
    const int ne = nc < CAP ? nc : CAP;
    for (int e = tid; e < ne; e += 256) {
        const int row = s_cand[e] >> 16;
        const int k   = s_cand[e] & 0xFFFF;
        if (s_cnt[row] > 1)
            resolve_cell(cb, c2g, &xs[0][0], s_x2e, s_res, row, k);
    }
    if (nc > CAP) {                               // pathological-tie fallback
#pragma unroll 1
        for (int row = wid; row < 64; row += 4)
            if (s_cnt[row] > 1)
#pragma unroll 1
                for (int k = lane; k < N_CODES; k += 64)
                    resolve_cell(cb, c2g, &xs[0][0], s_x2e, s_res, row, k);
    }
    __syncthreads();

    // --- output: wave wid writes rows wid*16..+15 (coalesced 256B each) -----
    const size_t n0 = (size_t)gw * 64;
#pragma unroll
    for (int rr = 0; rr < 16; ++rr) {
        const int row = (wid << 4) + rr;
        const int idx = (s_cnt[row] == 1) ? s_win[row]
                                          : (int)(s_res[row] & 0xFFFFFFFFull);
        out[(n0 + row) * CODE_DIM + lane] = cb[(size_t)idx * CODE_DIM + lane];
    }
}

// ---------------- fallback (R9, proven 190us) if ws too small ---------------
__device__ __forceinline__ float exact_dk_fb(const float* __restrict__ cb,
                                             const float* __restrict__ c2,
                                             const float (&x)[CODE_DIM], float x2, int k) {
    const float* crow = cb + (size_t)k * CODE_DIM;
    double a0 = 0.0, a1 = 0.0, a2 = 0.0, a3 = 0.0;
#pragma unroll
    for (int j = 0; j < CODE_DIM; j += 4) {
        a0 = fma((double)crow[j + 0], (double)x[j + 0], a0);
        a1 = fma((double)crow[j + 1], (double)x[j + 1], a1);
        a2 = fma((double)crow[j + 2], (double)x[j + 2], a2);
        a3 = fma((double)crow[j + 3], (double)x[j + 3], a3);
    }
    const double dot = (a0 + a1) + (a2 + a3);
    const float  ein = (float)dot;
    return __fsub_rn(__fadd_rn(x2, c2[k]), __fmul_rn(2.0f, ein));
}

__global__ __launch_bounds__(512, 2)
void vq_fallback_kernel(const float* __restrict__ in, const float* __restrict__ cb,
                        const float* __restrict__ c2, float* __restrict__ out) {
    __shared__ float s_rb[8][64];
    __shared__ int   s_ri[8][64];
    const int tid = threadIdx.x, lane = tid & 63, wid = tid >> 6;
    const int gw = blockIdx.x, b = gw >> 6, h = gw & 63;
    const float* xin = in + (size_t)b * B_STRIDE + (size_t)h * 64 + lane;
    float x[CODE_DIM];
#pragma unroll
    for (int c = 0; c < CODE_DIM; ++c) x[c] = xin[(size_t)c * CH_STRIDE];
    float r[8];
#pragma unroll
    for (int j = 0; j < 8; ++j) r[j] = __fmul_rn(x[j], x[j]);
#pragma unroll
    for (int i = 8; i < 64; i += 8)
#pragma unroll
        for (int j = 0; j < 8; ++j) r[j] = __fadd_rn(r[j], __fmul_rn(x[i + j], x[i + j]));
    const float x2 = __fadd_rn(__fadd_rn(__fadd_rn(r[0], r[1]), __fadd_rn(r[2], r[3])),
                               __fadd_rn(__fadd_rn(r[4], r[5]), __fadd_rn(r[6], r[7])));
    const int k0 = __builtin_amdgcn_readfirstlane(wid) * 64;
    float ex_best = INFINITY; int bi = k0;
#pragma unroll 1
    for (int kk = 0; kk < 64; ++kk) {
        const float dk = exact_dk_fb(cb, c2, x, x2, k0 + kk);
        if (dk < ex_best) { ex_best = dk; bi = k0 + kk; }
    }
    s_rb[wid][lane] = ex_best; s_ri[wid][lane] = bi;
    __syncthreads();
    float fb2 = s_rb[0][lane]; int fi = s_ri[0][lane];
#pragma unroll
    for (int w = 1; w < 8; ++w) {
        if (s_rb[w][lane] < fb2) { fb2 = s_rb[w][lane]; fi = s_ri[w][lane]; }
    }
    const size_t n0 = (size_t)gw * 64;
#pragma unroll 1
    for (int rr = 0; rr < 8; ++rr) {
        const int row = wid * 8 + rr;
        const int idxr = __shfl(fi, row, 64);
        out[(n0 + row) * CODE_DIM + lane] = cb[(size_t)idxr * CODE_DIM + lane];
    }
}

extern "C" void kernel_launch(void* const* d_in, const int* in_sizes, int n_in,
                              void* d_out, int out_size, void* d_ws, size_t ws_size,
                              hipStream_t stream) {
    const float* in  = (const float*)d_in[0];   // (16,64,64,64) fp32
    const float* cb  = (const float*)d_in[1];   // (512,64) fp32
    float*       out = (float*)d_out;           // (16,64,64,64) fp32

    float* c2 = (float*)d_ws;                                    // 2 KB
    unsigned short* bh = (unsigned short*)((char*)d_ws + 2048);  // 64 KB f16-hi frags
    const bool hasT = ws_size >= (size_t)(2048 + 65536);         // 66.5 KB

    vq_setup_kernel<<<dim3(64), dim3(64), 0, stream>>>(cb, c2, bh, hasT ? 1 : 0);
    if (hasT) {
        // 1024 blocks = one (b,h) group (64 rows) each; 256 threads = 4 waves.
        vq_block_kernel<<<dim3(1024), dim3(256), 0, stream>>>(in, cb, c2, bh, out);
    } else {
        vq_fallback_kernel<<<dim3(1024), dim3(512), 0, stream>>>(in, cb, c2, out);
    }
}